// Round 5
// baseline (110.676 us; speedup 1.0000x reference)
//
#include <hip/hip_runtime.h>

#define T_TOTAL 4194304
#define S 8                        // timesteps per thread (one segment)
#define NTHREADS 256
#define BLOCK_T (NTHREADS * S)     // 2048 timesteps per block
#define HALO_SEG 8                 // 8 segs * 8 steps = 64 warmup; ||A^64|| ~ 1e-8
#define NSEG (NTHREADS + HALO_SEG) // 264

struct M22 { float m00, m01, m10, m11; };
__device__ __forceinline__ M22 mmul(const M22& X, const M22& Y) {
    M22 r;
    r.m00 = fmaf(X.m00, Y.m00, X.m01 * Y.m10);
    r.m01 = fmaf(X.m00, Y.m01, X.m01 * Y.m11);
    r.m10 = fmaf(X.m10, Y.m00, X.m11 * Y.m10);
    r.m11 = fmaf(X.m10, Y.m01, X.m11 * Y.m11);
    return r;
}

struct alignas(16) F8 { float f[8]; };
__device__ __forceinline__ void load8(F8& d, const float* __restrict__ p) {
    const float4* q = (const float4*)p;   // all bases are 32B-aligned (t % 8 == 0)
    float4 a = q[0], b = q[1];
    *(float4*)&d.f[0] = a;
    *(float4*)&d.f[4] = b;
}

__global__ __launch_bounds__(NTHREADS)   // aim ~80 VGPR -> ~6 blocks/CU resident
void pinn_rnn_kernel(const float* __restrict__ x0p,
                     const float* __restrict__ u,
                     const float* __restrict__ td,
                     const float* __restrict__ WA,
                     const float* __restrict__ bA,
                     const float* __restrict__ WB,
                     const float* __restrict__ bB,
                     float* __restrict__ out)
{
    __shared__ float2 lc[NSEG];   // per-segment zero-state response (2.1 KB; only LDS)

    const int tid = threadIdx.x;
    const int B0  = blockIdx.x * BLOCK_T;

    const float a00 = WA[0], a01 = WA[1], a10 = WA[2], a11 = WA[3];
    const float w00 = WB[0], w01 = WB[1], w10 = WB[2], w11 = WB[3];
    const float bc0 = bA[0] + bB[0];
    const float bc1 = bA[1] + bB[1];

    const float* u0 = u;
    const float* u1 = u + T_TOTAL;

    // ---- issue ALL global loads upfront (max outstanding, latency overlap) ----
    const int t0 = B0 + tid * S;
    F8 U0, U1, DT;
    load8(U0, u0 + t0);
    load8(U1, u1 + t0);
    load8(DT, td + t0);

    F8 H0, H1;                                   // halo (lanes 0..7 only)
    const bool halo_owner = (tid < HALO_SEG);
    if (halo_owner && blockIdx.x != 0) {
        const int th = B0 - HALO_SEG * S + tid * S;
        load8(H0, u0 + th);
        load8(H1, u1 + th);
    }

    // ---- A^8 (uniform, ~24 fma; only power needed thanks to Horner) ----
    M22 A  = { a00, a01, a10, a11 };
    M22 A2 = mmul(A,  A );
    M22 A4 = mmul(A2, A2);
    M22 A8 = mmul(A4, A4);

    // ---- phase 1: zero-state response of own segment ----
    {
        float x0v = 0.f, x1v = 0.f;
        #pragma unroll
        for (int j = 0; j < S; ++j) {
            float v0 = fmaf(w00, U0.f[j], fmaf(w01, U1.f[j], bc0));
            float v1 = fmaf(w10, U0.f[j], fmaf(w11, U1.f[j], bc1));
            float n0 = fmaf(a00, x0v, fmaf(a01, x1v, v0));
            float n1 = fmaf(a10, x0v, fmaf(a11, x1v, v1));
            x0v = n0; x1v = n1;
        }
        lc[tid + HALO_SEG] = make_float2(x0v, x1v);
    }
    // halo segments (8 per block); block 0 has nothing before t=0
    if (halo_owner) {
        float2 ch = make_float2(0.f, 0.f);
        if (blockIdx.x != 0) {
            float x0v = 0.f, x1v = 0.f;
            #pragma unroll
            for (int j = 0; j < S; ++j) {
                float v0 = fmaf(w00, H0.f[j], fmaf(w01, H1.f[j], bc0));
                float v1 = fmaf(w10, H0.f[j], fmaf(w11, H1.f[j], bc1));
                float n0 = fmaf(a00, x0v, fmaf(a01, x1v, v0));
                float n1 = fmaf(a10, x0v, fmaf(a11, x1v, v1));
                x0v = n0; x1v = n1;
            }
            ch = make_float2(x0v, x1v);
        }
        lc[tid] = ch;
    }
    __syncthreads();   // the ONLY barrier

    // ---- x_in via Horner: c_{g-1} + A8(c_{g-2} + A8(... + A8 c_{g-8})) ----
    float xh0 = lc[tid].x, xh1 = lc[tid].y;          // c_{g-8}
    #pragma unroll
    for (int k = 1; k < HALO_SEG; ++k) {
        float2 ck = lc[tid + k];
        float n0 = ck.x + fmaf(A8.m00, xh0, A8.m01 * xh1);
        float n1 = ck.y + fmaf(A8.m10, xh0, A8.m11 * xh1);
        xh0 = n0; xh1 = n1;
    }
    // block 0, lanes 0..7: exact A^(8*tid) * x_0 term (divergent <=7-iter loop)
    if (blockIdx.x == 0 && halo_owner) {
        float v0 = x0p[0], v1 = x0p[1];
        for (int k = 0; k < tid; ++k) {
            float n0 = fmaf(A8.m00, v0, A8.m01 * v1);
            float n1 = fmaf(A8.m10, v0, A8.m11 * v1);
            v0 = n0; v1 = n1;
        }
        xh0 += v0; xh1 += v1;
    }

    // ---- phase 2: replay from x_in, pack 2 steps -> one float4 store ----
    float x0v = xh0, x1v = xh1;
    float4* og = (float4*)out + (B0 >> 1) + tid * (S / 2);
    #pragma unroll
    for (int p = 0; p < S / 2; ++p) {
        float o[4];
        #pragma unroll
        for (int q = 0; q < 2; ++q) {
            int j = 2 * p + q;
            float v0 = fmaf(w00, U0.f[j], fmaf(w01, U1.f[j], bc0));
            float v1 = fmaf(w10, U0.f[j], fmaf(w11, U1.f[j], bc1));
            float n0 = fmaf(a00, x0v, fmaf(a01, x1v, v0));
            float n1 = fmaf(a10, x0v, fmaf(a11, x1v, v1));
            float cc = U0.f[j] * DT.f[j];
            float sn, cs;
            __sincosf(U1.f[j], &sn, &cs);
            o[2 * q]     = fmaf(cc, cs, x0v) - n0;
            o[2 * q + 1] = fmaf(cc, sn, x1v) - n1;
            x0v = n0; x1v = n1;
        }
        og[p] = make_float4(o[0], o[1], o[2], o[3]);
    }
}

extern "C" void kernel_launch(void* const* d_in, const int* in_sizes, int n_in,
                              void* d_out, int out_size, void* d_ws, size_t ws_size,
                              hipStream_t stream) {
    const float* x0p = (const float*)d_in[0];
    const float* u   = (const float*)d_in[1];
    const float* td  = (const float*)d_in[2];
    const float* WA  = (const float*)d_in[3];
    const float* bA  = (const float*)d_in[4];
    const float* WB  = (const float*)d_in[5];
    const float* bB  = (const float*)d_in[6];
    float* outp = (float*)d_out;

    dim3 grid(T_TOTAL / BLOCK_T);   // 2048 short blocks: continuous dispatch
    dim3 block(NTHREADS);           // smooths load/compute/store bursts
    pinn_rnn_kernel<<<grid, block, 0, stream>>>(x0p, u, td, WA, bA, WB, bB, outp);
}

// Round 6
// 104.855 us; speedup vs baseline: 1.0555x; 1.0555x over previous
//
#include <hip/hip_runtime.h>

#define T_TOTAL 4194304
#define S 16                       // timesteps per thread (one segment)
#define NTHREADS 256
#define BLOCK_T (NTHREADS * S)     // 4096 timesteps per window
#define WPB 2                      // windows per block (software pipeline)
#define HALO_SEG 4                 // 64 warmup steps; ||A^64|| ~ 1e-8
#define NSEG (NTHREADS + HALO_SEG) // 260

struct M22 { float m00, m01, m10, m11; };
__device__ __forceinline__ M22 mmul(const M22& X, const M22& Y) {
    M22 r;
    r.m00 = fmaf(X.m00, Y.m00, X.m01 * Y.m10);
    r.m01 = fmaf(X.m00, Y.m01, X.m01 * Y.m11);
    r.m10 = fmaf(X.m10, Y.m00, X.m11 * Y.m10);
    r.m11 = fmaf(X.m10, Y.m01, X.m11 * Y.m11);
    return r;
}

struct alignas(16) F16 { float f[16]; };
__device__ __forceinline__ void load16(F16& d, const float* __restrict__ p) {
    const float4* q = (const float4*)p;     // bases 64B-aligned (t % 16 == 0)
    float4 a0 = q[0], a1 = q[1], a2 = q[2], a3 = q[3];
    *(float4*)&d.f[0]  = a0;
    *(float4*)&d.f[4]  = a1;
    *(float4*)&d.f[8]  = a2;
    *(float4*)&d.f[12] = a3;
}

__global__ __launch_bounds__(NTHREADS, 2)   // 2 blocks/CU (LDS 70KB), VGPR<=256
void pinn_rnn_kernel(const float* __restrict__ x0p,
                     const float* __restrict__ u,
                     const float* __restrict__ td,
                     const float* __restrict__ WA,
                     const float* __restrict__ bA,
                     const float* __restrict__ WB,
                     const float* __restrict__ bB,
                     float* __restrict__ out)
{
    __shared__ float2 lc0[NSEG], lc1[NSEG];        // zero-state responses (2x2KB)
    __shared__ float2 lout0[BLOCK_T], lout1[BLOCK_T]; // output transposes (2x32KB)

    const int tid = threadIdx.x;
    const int B0  = blockIdx.x * (WPB * BLOCK_T);  // window 0 start
    const int B1  = B0 + BLOCK_T;                  // window 1 start

    const float a00 = WA[0], a01 = WA[1], a10 = WA[2], a11 = WA[3];
    const float w00 = WB[0], w01 = WB[1], w10 = WB[2], w11 = WB[3];
    const float bc0 = bA[0] + bB[0];
    const float bc1 = bA[1] + bB[1];

    const float* u0 = u;
    const float* u1 = u + T_TOTAL;

    // ---- W0 loads (own chunk + halo) ----
    const int t0 = B0 + tid * S;
    F16 U0a, U1a, DTa;
    load16(U0a, u0 + t0);
    load16(U1a, u1 + t0);
    load16(DTa, td + t0);

    F16 H0, H1;
    float X0 = 0.f, X1 = 0.f;
    const bool halo_owner = (tid < HALO_SEG);
    if (halo_owner) {
        if (blockIdx.x != 0) {
            const int th = B0 - HALO_SEG * S + tid * S;
            load16(H0, u0 + th);
            load16(H1, u1 + th);
        } else {
            X0 = x0p[0]; X1 = x0p[1];
            #pragma unroll
            for (int o = 0; o < 4; ++o) { *(float4*)&H0.f[o*4] = make_float4(0,0,0,0);
                                          *(float4*)&H1.f[o*4] = make_float4(0,0,0,0); }
        }
    }

    // ---- powers of A (uniform) ----
    M22 A   = { a00, a01, a10, a11 };
    M22 A2  = mmul(A,  A );
    M22 A4  = mmul(A2, A2);
    M22 A8  = mmul(A4, A4);
    M22 M   = mmul(A8, A8);   // A^16
    M22 Mp2 = mmul(M,  M );   // A^32
    M22 Mp3 = mmul(Mp2, M);   // A^48

    // ---- phase 1 (W0): zero-state responses ----
    {
        float x0v = 0.f, x1v = 0.f;
        #pragma unroll
        for (int j = 0; j < S; ++j) {
            float v0 = fmaf(w00, U0a.f[j], fmaf(w01, U1a.f[j], bc0));
            float v1 = fmaf(w10, U0a.f[j], fmaf(w11, U1a.f[j], bc1));
            float n0 = fmaf(a00, x0v, fmaf(a01, x1v, v0));
            float n1 = fmaf(a10, x0v, fmaf(a11, x1v, v1));
            x0v = n0; x1v = n1;
        }
        lc0[tid + HALO_SEG] = make_float2(x0v, x1v);
    }
    if (halo_owner) {
        float x0v = 0.f, x1v = 0.f;
        #pragma unroll
        for (int j = 0; j < S; ++j) {
            float v0 = fmaf(w00, H0.f[j], fmaf(w01, H1.f[j], bc0));
            float v1 = fmaf(w10, H0.f[j], fmaf(w11, H1.f[j], bc1));
            float n0 = fmaf(a00, x0v, fmaf(a01, x1v, v0));
            float n1 = fmaf(a10, x0v, fmaf(a11, x1v, v1));
            x0v = n0; x1v = n1;
        }
        lc0[tid] = make_float2(x0v, x1v);   // block 0 staged zeros -> c = 0-ish? no:
        if (blockIdx.x == 0) lc0[tid] = make_float2(0.f, 0.f);
    }

    // ---- issue W1 loads NOW: they drain while W0 phase-2/stores run ----
    const int t1 = B1 + tid * S;
    F16 U0b, U1b, DTb;
    load16(U0b, u0 + t1);
    load16(U1b, u1 + t1);
    load16(DTb, td + t1);

    __syncthreads();   // A: lc0 ready

    // W1's halo c's are W0's last 4 segment c's — no loads, no compute
    if (halo_owner) lc1[tid] = lc0[NTHREADS + tid];

    // ---- x_in(W0) + phase 2 (W0) into swizzled lout0 ----
    {
        float2 c1 = lc0[tid + 3], c2 = lc0[tid + 2], c3 = lc0[tid + 1], c4 = lc0[tid];
        float xi0 = c1.x
                  + fmaf(M.m00,   c2.x, M.m01   * c2.y)
                  + fmaf(Mp2.m00, c3.x, Mp2.m01 * c3.y)
                  + fmaf(Mp3.m00, c4.x, Mp3.m01 * c4.y);
        float xi1 = c1.y
                  + fmaf(M.m10,   c2.x, M.m11   * c2.y)
                  + fmaf(Mp2.m10, c3.x, Mp2.m11 * c3.y)
                  + fmaf(Mp3.m10, c4.x, Mp3.m11 * c4.y);
        if (blockIdx.x == 0 && halo_owner) {   // exact A^(16*tid) * x_0
            M22 P;
            if      (tid == 0) P = { 1.f, 0.f, 0.f, 1.f };
            else if (tid == 1) P = M;
            else if (tid == 2) P = Mp2;
            else               P = Mp3;
            xi0 += fmaf(P.m00, X0, P.m01 * X1);
            xi1 += fmaf(P.m10, X0, P.m11 * X1);
        }
        const int xm = tid & 14;
        float2* lrow = lout0 + tid * S;
        float x0v = xi0, x1v = xi1;
        #pragma unroll
        for (int j = 0; j < S; ++j) {
            float v0 = fmaf(w00, U0a.f[j], fmaf(w01, U1a.f[j], bc0));
            float v1 = fmaf(w10, U0a.f[j], fmaf(w11, U1a.f[j], bc1));
            float n0 = fmaf(a00, x0v, fmaf(a01, x1v, v0));
            float n1 = fmaf(a10, x0v, fmaf(a11, x1v, v1));
            float cc = U0a.f[j] * DTa.f[j];
            float sn, cs;
            __sincosf(U1a.f[j], &sn, &cs);
            lrow[j ^ xm] = make_float2(fmaf(cc, cs, x0v) - n0,
                                       fmaf(cc, sn, x1v) - n1);
            x0v = n0; x1v = n1;
        }
    }
    __syncthreads();   // B: lout0 + lc1[0..3] ready

    // ---- copy-out W0 (coalesced), then phase 1 (W1) ----
    {
        const float4* lo4 = (const float4*)lout0;
        float4* og = (float4*)out + (B0 >> 1);
        #pragma unroll
        for (int m = 0; m < 8; ++m) {
            int f    = m * NTHREADS + tid;
            int i0   = f << 1;
            int slot = i0 ^ ((i0 >> 4) & 14);
            og[f] = lo4[slot >> 1];
        }
    }
    {
        float x0v = 0.f, x1v = 0.f;
        #pragma unroll
        for (int j = 0; j < S; ++j) {
            float v0 = fmaf(w00, U0b.f[j], fmaf(w01, U1b.f[j], bc0));
            float v1 = fmaf(w10, U0b.f[j], fmaf(w11, U1b.f[j], bc1));
            float n0 = fmaf(a00, x0v, fmaf(a01, x1v, v0));
            float n1 = fmaf(a10, x0v, fmaf(a11, x1v, v1));
            x0v = n0; x1v = n1;
        }
        lc1[tid + HALO_SEG] = make_float2(x0v, x1v);
    }
    __syncthreads();   // C: lc1 ready

    // ---- x_in(W1) + phase 2 (W1) into swizzled lout1 ----
    {
        float2 c1 = lc1[tid + 3], c2 = lc1[tid + 2], c3 = lc1[tid + 1], c4 = lc1[tid];
        float xi0 = c1.x
                  + fmaf(M.m00,   c2.x, M.m01   * c2.y)
                  + fmaf(Mp2.m00, c3.x, Mp2.m01 * c3.y)
                  + fmaf(Mp3.m00, c4.x, Mp3.m01 * c4.y);
        float xi1 = c1.y
                  + fmaf(M.m10,   c2.x, M.m11   * c2.y)
                  + fmaf(Mp2.m10, c3.x, Mp2.m11 * c3.y)
                  + fmaf(Mp3.m10, c4.x, Mp3.m11 * c4.y);
        const int xm = tid & 14;
        float2* lrow = lout1 + tid * S;
        float x0v = xi0, x1v = xi1;
        #pragma unroll
        for (int j = 0; j < S; ++j) {
            float v0 = fmaf(w00, U0b.f[j], fmaf(w01, U1b.f[j], bc0));
            float v1 = fmaf(w10, U0b.f[j], fmaf(w11, U1b.f[j], bc1));
            float n0 = fmaf(a00, x0v, fmaf(a01, x1v, v0));
            float n1 = fmaf(a10, x0v, fmaf(a11, x1v, v1));
            float cc = U0b.f[j] * DTb.f[j];
            float sn, cs;
            __sincosf(U1b.f[j], &sn, &cs);
            lrow[j ^ xm] = make_float2(fmaf(cc, cs, x0v) - n0,
                                       fmaf(cc, sn, x1v) - n1);
            x0v = n0; x1v = n1;
        }
    }
    __syncthreads();   // D: lout1 ready

    // ---- copy-out W1 (coalesced) ----
    {
        const float4* lo4 = (const float4*)lout1;
        float4* og = (float4*)out + (B1 >> 1);
        #pragma unroll
        for (int m = 0; m < 8; ++m) {
            int f    = m * NTHREADS + tid;
            int i0   = f << 1;
            int slot = i0 ^ ((i0 >> 4) & 14);
            og[f] = lo4[slot >> 1];
        }
    }
}

extern "C" void kernel_launch(void* const* d_in, const int* in_sizes, int n_in,
                              void* d_out, int out_size, void* d_ws, size_t ws_size,
                              hipStream_t stream) {
    const float* x0p = (const float*)d_in[0];
    const float* u   = (const float*)d_in[1];
    const float* td  = (const float*)d_in[2];
    const float* WA  = (const float*)d_in[3];
    const float* bA  = (const float*)d_in[4];
    const float* WB  = (const float*)d_in[5];
    const float* bB  = (const float*)d_in[6];
    float* outp = (float*)d_out;

    dim3 grid(T_TOTAL / (WPB * BLOCK_T));   // 512 blocks, 2 pipelined windows each
    dim3 block(NTHREADS);
    pinn_rnn_kernel<<<grid, block, 0, stream>>>(x0p, u, td, WA, bA, WB, bB, outp);
}